// Round 3
// baseline (631.530 us; speedup 1.0000x reference)
//
#include <hip/hip_runtime.h>
#include <hip/hip_bf16.h>
#include <cmath>

// Problem constants
constexpr int Bc  = 2;
constexpr int Sc  = 2048;
constexpr int Dc  = 768;
constexpr int Hc  = 12;
constexpr int Ec  = 64;          // d_head
constexpr int BSc = Bc * Sc;     // 4096

typedef _Float16 f16;
typedef __attribute__((ext_vector_type(8)))  _Float16 half8;    // MFMA A/B frag (4 VGPR)
typedef __attribute__((ext_vector_type(16))) float    floatx16; // MFMA C/D (16 VGPR)

typedef __attribute__((address_space(3))) void       lds_void;
typedef __attribute__((address_space(1))) const void glb_cvoid;

// K swizzle: blob per (hb, kt(64), ks(4)), 512 halves: lane(hf*32+col)*8+j =
//   K[hb][key=kt*32+col][e=ks*16+hf*8+j]
// V swizzle: blob per (hb, kt(64), ks2(2), vh(2)), 512 halves: lane*8+j =
//   V[hb][key=kt*32+ks2*16+hf*8+j][e=vh*32+col]   (i.e. V^T fragment order)
//
// GEMM LDS tiles use a T2-style XOR swizzle (both-sides-or-neither, rule #21):
// global source column is pre-swizzled per lane (lseg ^ lrow) so the LINEAR
// global_load_lds write lands element (row, col ^ ((row&7)<<3)) at LDS slot
// (row, col); fragment reads apply the same XOR. Kills the 32-way bank
// conflict of the 128 B-pitch column read.
//
// GEMM K-loop is now double-buffered (T3-minimum 2-phase): STAGE(t+1) is
// issued BEFORE computing tile t, one barrier per step, so the global->LDS
// latency hides under the MFMA block instead of being drained serially.

// ---------------------------------------------------------------------------
// Kernel 0: prep — x fp32->fp16; W transposes to B-operand [n][k] fp16; bias.
// ---------------------------------------------------------------------------
__global__ __launch_bounds__(256) void prep_kernel(
    const float* __restrict__ x,
    const float* __restrict__ Wq, const float* __restrict__ Wk, const float* __restrict__ Wv,
    const float* __restrict__ bq, const float* __restrict__ bk, const float* __restrict__ bv,
    const float* __restrict__ Wo,
    f16* __restrict__ x16, f16* __restrict__ Wt16, f16* __restrict__ Wot16,
    float* __restrict__ bias_cat)
{
    __shared__ __align__(16) float Ts[64][65];
    const int t = threadIdx.x;
    int bid = blockIdx.x;

    if (bid < 1536) {          // ---- x convert ----
        const size_t base = (size_t)bid * 2048 + t * 8;
        const float4 v0 = *(const float4*)(x + base);
        const float4 v1 = *(const float4*)(x + base + 4);
        half8 hv;
        hv[0] = (f16)v0.x; hv[1] = (f16)v0.y; hv[2] = (f16)v0.z; hv[3] = (f16)v0.w;
        hv[4] = (f16)v1.x; hv[5] = (f16)v1.y; hv[6] = (f16)v1.z; hv[7] = (f16)v1.w;
        *(half8*)(x16 + base) = hv;
        return;
    }
    bid -= 1536;
    if (bid < 432) {           // ---- qkv weight transpose ----
        const int proj = bid / 144, rem = bid % 144, h = rem / 12, dt = rem % 12;
        const float* W = ((proj == 0) ? Wq : (proj == 1) ? Wk : Wv) + (size_t)h * Dc * Ec;
        const int c = t & 63, rr = t >> 6;
        #pragma unroll
        for (int r0 = 0; r0 < 64; r0 += 4) {
            const int d = rr + r0;
            Ts[d][c] = W[(size_t)(dt * 64 + d) * Ec + c];
        }
        __syncthreads();
        #pragma unroll
        for (int r0 = 0; r0 < 64; r0 += 4) {
            const int e = rr + r0;
            Wt16[(size_t)(proj * 768 + h * 64 + e) * Dc + dt * 64 + c] = (f16)Ts[c][e];
        }
        return;
    }
    bid -= 432;
    if (bid < 144) {           // ---- Wo transpose ----
        const int rt = bid / 12, ct = bid % 12;
        const int c = t & 63, rr = t >> 6;
        #pragma unroll
        for (int r0 = 0; r0 < 64; r0 += 4) {
            const int d = rr + r0;
            Ts[d][c] = Wo[(size_t)(rt * 64 + d) * Dc + ct * 64 + c];
        }
        __syncthreads();
        #pragma unroll
        for (int r0 = 0; r0 < 64; r0 += 4) {
            const int e = rr + r0;
            Wot16[(size_t)(ct * 64 + e) * Dc + rt * 64 + c] = (f16)Ts[c][e];
        }
        return;
    }
    bid -= 144;
    {                          // ---- bias concat ----
        const int g = bid * 256 + t;
        if (g < 3 * 768) {
            const int proj = g / 768, idx = g % 768;
            const float* bb = (proj == 0) ? bq : (proj == 1) ? bk : bv;
            bias_cat[g] = bb[idx];
        }
    }
}

// ---------------------------------------------------------------------------
// Kernel 1: QKV GEMM (fp16 MFMA, double-buffered global_load_lds staging,
// XOR-swizzled LDS).
// ---------------------------------------------------------------------------
__global__ __launch_bounds__(256, 2) void gemm_qkv_kernel(
    const f16* __restrict__ x16, const f16* __restrict__ Wt16,
    const float* __restrict__ bias_cat,
    f16* __restrict__ q16, f16* __restrict__ kswz, f16* __restrict__ vswz)
{
    __shared__ __align__(16) unsigned char smem[65536];
    // buf b: As at b*32768, Bs at b*32768+16384 (each 128x64 f16 = 16384 B)
    f16 (*Cs)[136] = (f16(*)[136])smem;             // 128 x 136 = 34816 B (post-loop)

    const int t = threadIdx.x;
    const int wave = t >> 6, lane = t & 63;
    const int col = lane & 31, hf = lane >> 5;
    const int wr = wave & 1, wc = wave >> 1;
    const int m0 = blockIdx.x * 128, n0 = blockIdx.y * 128;
    const int lrow = lane >> 3, lseg = lane & 7;    // staging: 8 lanes per row
    const int sseg = lseg ^ lrow;                   // pre-swizzled source column
    const int sw   = (col & 7) << 3;                // read-side XOR (half index)

    floatx16 c00, c01, c10, c11;
    #pragma unroll
    for (int i = 0; i < 16; ++i) { c00[i] = 0.f; c01[i] = 0.f; c10[i] = 0.f; c11[i] = 0.f; }

#define QKV_STAGE(BUF, K0)                                                     \
    do {                                                                       \
        f16 (*As_)[64] = (f16(*)[64])(smem + (BUF) * 32768);                   \
        f16 (*Bs_)[64] = (f16(*)[64])(smem + (BUF) * 32768 + 16384);           \
        _Pragma("unroll")                                                      \
        for (int i_ = 0; i_ < 4; ++i_) {                                       \
            const int r_ = wave * 32 + i_ * 8;                                 \
            __builtin_amdgcn_global_load_lds(                                  \
                (glb_cvoid*)(x16 + (size_t)(m0 + r_ + lrow) * Dc + (K0) + sseg * 8), \
                (lds_void*)&As_[r_][0], 16, 0, 0);                             \
            __builtin_amdgcn_global_load_lds(                                  \
                (glb_cvoid*)(Wt16 + (size_t)(n0 + r_ + lrow) * Dc + (K0) + sseg * 8), \
                (lds_void*)&Bs_[r_][0], 16, 0, 0);                             \
        }                                                                      \
    } while (0)

    QKV_STAGE(0, 0);
    __syncthreads();
    for (int tt = 0; tt < 12; ++tt) {
        if (tt + 1 < 12) QKV_STAGE((tt + 1) & 1, (tt + 1) * 64);
        f16 (*As)[64] = (f16(*)[64])(smem + (tt & 1) * 32768);
        f16 (*Bs)[64] = (f16(*)[64])(smem + (tt & 1) * 32768 + 16384);
        #pragma unroll
        for (int ks = 0; ks < 4; ++ks) {
            const int fo = (ks * 16 + hf * 8) ^ sw;
            const half8 a0 = *(const half8*)&As[wr * 64 + col][fo];
            const half8 a1 = *(const half8*)&As[wr * 64 + 32 + col][fo];
            const half8 b0 = *(const half8*)&Bs[wc * 64 + col][fo];
            const half8 b1 = *(const half8*)&Bs[wc * 64 + 32 + col][fo];
            c00 = __builtin_amdgcn_mfma_f32_32x32x16_f16(a0, b0, c00, 0, 0, 0);
            c01 = __builtin_amdgcn_mfma_f32_32x32x16_f16(a0, b1, c01, 0, 0, 0);
            c10 = __builtin_amdgcn_mfma_f32_32x32x16_f16(a1, b0, c10, 0, 0, 0);
            c11 = __builtin_amdgcn_mfma_f32_32x32x16_f16(a1, b1, c11, 0, 0, 0);
        }
        __syncthreads();   // next-tile staging complete; all reads of old buf done
    }
#undef QKV_STAGE

    const float bias0 = bias_cat[n0 + wc * 64 + col];
    const float bias1 = bias_cat[n0 + wc * 64 + 32 + col];
    #pragma unroll
    for (int i = 0; i < 16; ++i) {
        const int r = (i & 3) + 8 * (i >> 2) + 4 * hf;
        Cs[wr * 64 + r][wc * 64 + col]           = (f16)(c00[i] + bias0);
        Cs[wr * 64 + r][wc * 64 + 32 + col]      = (f16)(c01[i] + bias1);
        Cs[wr * 64 + 32 + r][wc * 64 + col]      = (f16)(c10[i] + bias0);
        Cs[wr * 64 + 32 + r][wc * 64 + 32 + col] = (f16)(c11[i] + bias1);
    }
    __syncthreads();

    const int proj = n0 / 768;
    const int h0   = (n0 - proj * 768) >> 6;   // first of two heads in this tile
    const int b    = m0 >> 11;
    const int s_in = m0 & 2047;
    const int kt0  = s_in >> 5;                // first of 4 key-tiles in m-range

    if (proj == 0) {
        const int row = t >> 1, seg = t & 1;
        const int h = h0 + seg;
        f16* gp = q16 + ((size_t)(h * Bc + b) * Sc + s_in + row) * Ec;
        #pragma unroll
        for (int j = 0; j < 8; ++j)
            *(half8*)(gp + j * 8) = *(const half8*)&Cs[row][seg * 64 + j * 8];
    } else if (proj == 1) {
        #pragma unroll
        for (int ch = 0; ch < 8; ++ch) {
            const int id = ch * 256 + t;            // 0..2047
            const int lane_ = id & 63;
            const int ks  = (id >> 6) & 3;
            const int ktp = (id >> 8) & 3;
            const int seg = (id >> 10) & 1;
            const int colp = lane_ & 31, hfp = lane_ >> 5;
            const int hb = (h0 + seg) * Bc + b;
            const half8 val = *(const half8*)&Cs[ktp * 32 + colp][seg * 64 + ks * 16 + hfp * 8];
            *(half8*)(kswz + ((size_t)((hb * 64 + kt0 + ktp) * 4 + ks) << 9) + lane_ * 8) = val;
        }
    } else {
        #pragma unroll
        for (int ch = 0; ch < 8; ++ch) {
            const int id = ch * 256 + t;
            const int lane_ = id & 63;
            const int ks2 = (id >> 6) & 1;
            const int vh  = (id >> 7) & 1;
            const int ktp = (id >> 8) & 3;
            const int seg = (id >> 10) & 1;
            const int colp = lane_ & 31, hfp = lane_ >> 5;
            const int hb = (h0 + seg) * Bc + b;
            const int e  = vh * 32 + colp;
            half8 val;
            #pragma unroll
            for (int j = 0; j < 8; ++j)
                val[j] = Cs[ktp * 32 + ks2 * 16 + hfp * 8 + j][seg * 64 + e];
            *(half8*)(vswz + ((size_t)(((hb * 64 + kt0 + ktp) * 2 + ks2) * 2 + vh) << 9) + lane_ * 8) = val;
        }
    }
}

// ---------------------------------------------------------------------------
// Kernel 2: fp16 MFMA flash attention. 128 threads = 2 waves; each wave owns
// 32 query rows and sweeps ALL 2048 keys (no key-half split, no combine).
// Mask loads go direct to VGPRs (nontemporal), PREFETCH DISTANCE 2 (4 reg
// buffers): one tile body (~450 cy) is shorter than HBM latency (~900 cy),
// so distance-1 left a partial stall on every tile at 1.5 waves/SIMD.
// Main loop is barrier-free. Two-pass softmax.
// ---------------------------------------------------------------------------
__global__ __launch_bounds__(128, 2) void flash_attn_kernel(
    const f16* __restrict__ q16, const f16* __restrict__ kswz,
    const f16* __restrict__ vswz, const float* __restrict__ mask,
    f16* __restrict__ obuf16)
{
    __shared__ _Float16 Plds[2][32][44];             // 5.5 KB per-wave P tiles

    // XCD-aware decode: xcd = fblk&7 ; 3 hb per XCD -> K/V L2-resident
    const int fblk = blockIdx.x;            // 0..767
    const int kk   = fblk >> 3;             // 0..95
    const int hb   = (fblk & 7) + 8 * (kk >> 5);   // 0..23
    const int rb   = kk & 31;
    const int h    = hb >> 1;
    const int b    = hb & 1;

    const int t    = threadIdx.x;
    const int wave = t >> 6;     // row group (0/1)
    const int lane = t & 63;
    const int col  = lane & 31;
    const int hf   = lane >> 5;
    const int row0 = rb * 64 + wave * 32;

    const f16* qb  = q16  + ((size_t)hb * Sc + row0) * Ec;
    const f16* kbz = kswz + ((size_t)hb << 17);
    const f16* vbz = vswz + ((size_t)hb << 17);
    const float* mband = mask + ((size_t)hb * Sc + rb * 64) * Sc;  // block's 64-row band

    half8 qfrag[4];
    #pragma unroll
    for (int ks = 0; ks < 4; ++ks)
        qfrag[ks] = *(const half8*)(qb + (size_t)col * Ec + ks * 16 + hf * 8);

    constexpr int NT = Sc / 32;   // 64 key tiles

    // ======== PASS 1: row max (mask <= 0 ⇒ exp(s-mrow) <= 1 stays safe) ====
    float vmax[16];
    #pragma unroll
    for (int i = 0; i < 16; ++i) vmax[i] = -3e38f;

    half8 kreg[4];
    {
        const f16* kp = kbz + lane * 8;
        #pragma unroll
        for (int ks = 0; ks < 4; ++ks) kreg[ks] = *(const half8*)(kp + (ks << 9));
    }
    #pragma unroll 2
    for (int kt = 0; kt < NT; ++kt) {
        floatx16 c;
        #pragma unroll
        for (int i = 0; i < 16; ++i) c[i] = 0.f;
        #pragma unroll
        for (int ks = 0; ks < 4; ++ks)
            c = __builtin_amdgcn_mfma_f32_32x32x16_f16(qfrag[ks], kreg[ks], c, 0, 0, 0);
        if (kt + 1 < NT) {
            const f16* kp = kbz + ((size_t)(kt + 1) << 11) + lane * 8;
            #pragma unroll
            for (int ks = 0; ks < 4; ++ks) kreg[ks] = *(const half8*)(kp + (ks << 9));
        }
        #pragma unroll
        for (int i = 0; i < 16; ++i) vmax[i] = fmaxf(vmax[i], c[i]);
    }
    float mrow[16];
    #pragma unroll
    for (int i = 0; i < 16; ++i) {
        float v = vmax[i];
        v = fmaxf(v, __shfl_xor(v, 1));
        v = fmaxf(v, __shfl_xor(v, 2));
        v = fmaxf(v, __shfl_xor(v, 4));
        v = fmaxf(v, __shfl_xor(v, 8));
        v = fmaxf(v, __shfl_xor(v, 16));
        mrow[i] = v;
    }

    // ======== PASS 2: exp + PV; mask in registers, 2 tiles ahead ==========
    floatx16 o0, o1;
    float lsum[16];
    #pragma unroll
    for (int i = 0; i < 16; ++i) { o0[i] = 0.f; o1[i] = 0.f; lsum[i] = 0.f; }

    // lane's mask base: rows (wave*32 + 4*hf + roff), column `col` of the band
    const float* mlane = mband + (size_t)(wave * 32 + 4 * hf) * Sc + col;

    float m0r[16], m1r[16], m2r[16], m3r[16];
    #pragma unroll
    for (int i = 0; i < 16; ++i)
        m0r[i] = __builtin_nontemporal_load(
            mlane + (size_t)((i & 3) + 8 * (i >> 2)) * Sc);
    #pragma unroll
    for (int i = 0; i < 16; ++i)
        m1r[i] = __builtin_nontemporal_load(
            mlane + 32 + (size_t)((i & 3) + 8 * (i >> 2)) * Sc);

    {   // K tile 0 prefetch (L2-fast, issued after the HBM mask loads)
        const f16* kp = kbz + lane * 8;
        #pragma unroll
        for (int ks = 0; ks < 4; ++ks) kreg[ks] = *(const half8*)(kp + (ks << 9));
    }

    // Tile body. Issue order: V(kt) -> mask(kt+2) -> QK mfma -> K(kt+1) ->
    // exp(consumes mask(kt), issued TWO tile-bodies ago) -> PV.
#define ATT_TILE(KT, MC, MN)                                                   \
    do {                                                                       \
        const int kt_ = (KT);                                                  \
        const f16* vp_ = vbz + ((size_t)kt_ << 11) + lane * 8;                 \
        const half8 va_ = *(const half8*)(vp_);                                \
        const half8 vb_ = *(const half8*)(vp_ + (1 << 9));                     \
        const half8 vc_ = *(const half8*)(vp_ + (2 << 9));                     \
        const half8 vd_ = *(const half8*)(vp_ + (3 << 9));                     \
        if (kt_ + 2 < NT) {                                                    \
            const float* mp_ = mlane + (kt_ + 2) * 32;                         \
            _Pragma("unroll")                                                  \
            for (int i = 0; i < 16; ++i)                                       \
                MN[i] = __builtin_nontemporal_load(                            \
                    mp_ + (size_t)((i & 3) + 8 * (i >> 2)) * Sc);              \
        }                                                                      \
        floatx16 c_;                                                           \
        _Pragma("unroll")                                                      \
        for (int i = 0; i < 16; ++i) c_[i] = 0.f;                              \
        _Pragma("unroll")                                                      \
        for (int ks = 0; ks < 4; ++ks)                                         \
            c_ = __builtin_amdgcn_mfma_f32_32x32x16_f16(qfrag[ks], kreg[ks],   \
                                                        c_, 0, 0, 0);          \
        if (kt_ + 1 < NT) {                                                    \
            const f16* kp_ = kbz + ((size_t)(kt_ + 1) << 11) + lane * 8;       \
            _Pragma("unroll")                                                  \
            for (int ks = 0; ks < 4; ++ks)                                     \
                kreg[ks] = *(const half8*)(kp_ + (ks << 9));                   \
        }                                                                      \
        _Pragma("unroll")                                                      \
        for (int i = 0; i < 16; ++i) {                                         \
            const int r_ = (i & 3) + 8 * (i >> 2) + 4 * hf;                    \
            const float p_ = __expf(c_[i] + MC[i] - mrow[i]);  /* <=1 */       \
            lsum[i] += p_;                                                     \
            Plds[wave][r_][col] = (f16)p_;                                     \
        }                                                                      \
        /* same-wave RAW through LDS (per-wave private slice) */               \
        asm volatile("s_waitcnt lgkmcnt(0)" ::: "memory");                     \
        _Pragma("unroll")                                                      \
        for (int ks2 = 0; ks2 < 2; ++ks2) {                                    \
            const half8 pf_ = *(const half8*)(&Plds[wave][col][ks2 * 16 + hf * 8]); \
            o0 = __builtin_amdgcn_mfma_f32_32x32x16_f16(                       \
                pf_, (ks2 == 0) ? va_ : vc_, o0, 0, 0, 0);                     \
            o1 = __builtin_amdgcn_mfma_f32_32x32x16_f16(                       \
                pf_, (ks2 == 0) ? vb_ : vd_, o1, 0, 0, 0);                     \
        }                                                                      \
    } while (0)

    for (int kt4 = 0; kt4 < NT; kt4 += 4) {
        ATT_TILE(kt4,     m0r, m2r);
        ATT_TILE(kt4 + 1, m1r, m3r);
        ATT_TILE(kt4 + 2, m2r, m0r);
        ATT_TILE(kt4 + 3, m3r, m1r);
    }
#undef ATT_TILE

    // final l reduction + normalize + store (no cross-wave combine needed)
    #pragma unroll
    for (int i = 0; i < 16; ++i) {
        float v = lsum[i];
        v += __shfl_xor(v, 1);
        v += __shfl_xor(v, 2);
        v += __shfl_xor(v, 4);
        v += __shfl_xor(v, 8);
        v += __shfl_xor(v, 16);
        const float inv = 1.f / v;
        const int r = (i & 3) + 8 * (i >> 2) + 4 * hf;
        const size_t orow = ((size_t)b * Sc + row0 + r) * Dc + h * Ec;
        obuf16[orow + col]      = (f16)(o0[i] * inv);
        obuf16[orow + 32 + col] = (f16)(o1[i] * inv);
    }
}

// ---------------------------------------------------------------------------
// Kernel 3: output GEMM (fp16 MFMA, double-buffered global_load_lds staging,
// XOR-swizzled LDS).
// ---------------------------------------------------------------------------
__global__ __launch_bounds__(256, 2) void gemm_out_kernel(
    const f16* __restrict__ a16, const f16* __restrict__ Wot16,
    const float* __restrict__ bo, float* __restrict__ out)
{
    __shared__ __align__(16) unsigned char smem[49152];
    // buf b: As at b*24576 (128x64 = 16384 B), Bs at b*24576+16384 (64x64 = 8192 B)

    const int t = threadIdx.x;
    const int wave = t >> 6, lane = t & 63;
    const int col = lane & 31, hf = lane >> 5;
    const int m0 = blockIdx.x * 128, n0 = blockIdx.y * 64;
    const int lrow = lane >> 3, lseg = lane & 7;
    const int sseg = lseg ^ lrow;                   // pre-swizzled source column
    const int sw   = (col & 7) << 3;                // read-side XOR (half index)

    floatx16 c0, c1;
    #pragma unroll
    for (int i = 0; i < 16; ++i) { c0[i] = 0.f; c1[i] = 0.f; }

#define OUT_STAGE(BUF, K0)                                                     \
    do {                                                                       \
        f16 (*As_)[64] = (f16(*)[64])(smem + (BUF) * 24576);                   \
        f16 (*Bs_)[64] = (f16(*)[64])(smem + (BUF) * 24576 + 16384);           \
        _Pragma("unroll")                                                      \
        for (int i_ = 0; i_ < 4; ++i_) {                                       \
            const int r_ = wave * 32 + i_ * 8;                                 \
            __builtin_amdgcn_global_load_lds(                                  \
                (glb_cvoid*)(a16 + (size_t)(m0 + r_ + lrow) * Dc + (K0) + sseg * 8), \
                (lds_void*)&As_[r_][0], 16, 0, 0);                             \
        }                                                                      \
        {                                                                      \
            const int r_ = wave * 16;                                          \
            __builtin_amdgcn_global_load_lds(                                  \
                (glb_cvoid*)(Wot16 + (size_t)(n0 + r_ + lrow) * Dc + (K0) + sseg * 8), \
                (lds_void*)&Bs_[r_][0], 16, 0, 0);                             \
            __builtin_amdgcn_global_load_lds(                                  \
                (glb_cvoid*)(Wot16 + (size_t)(n0 + r_ + 8 + lrow) * Dc + (K0) + sseg * 8), \
                (lds_void*)&Bs_[r_ + 8][0], 16, 0, 0);                         \
        }                                                                      \
    } while (0)

    OUT_STAGE(0, 0);
    __syncthreads();
    for (int tt = 0; tt < 12; ++tt) {
        if (tt + 1 < 12) OUT_STAGE((tt + 1) & 1, (tt + 1) * 64);
        f16 (*As)[64] = (f16(*)[64])(smem + (tt & 1) * 24576);
        f16 (*Bs)[64] = (f16(*)[64])(smem + (tt & 1) * 24576 + 16384);
        #pragma unroll
        for (int ks = 0; ks < 4; ++ks) {
            const int fo = (ks * 16 + hf * 8) ^ sw;
            const half8 a  = *(const half8*)&As[wave * 32 + col][fo];
            const half8 b0 = *(const half8*)&Bs[col][fo];
            const half8 b1 = *(const half8*)&Bs[32 + col][fo];
            c0 = __builtin_amdgcn_mfma_f32_32x32x16_f16(a, b0, c0, 0, 0, 0);
            c1 = __builtin_amdgcn_mfma_f32_32x32x16_f16(a, b1, c1, 0, 0, 0);
        }
        __syncthreads();
    }
#undef OUT_STAGE

    const float bo0 = bo[n0 + col], bo1 = bo[n0 + 32 + col];
    #pragma unroll
    for (int i = 0; i < 16; ++i) {
        const int r = (i & 3) + 8 * (i >> 2) + 4 * hf;
        const size_t ro = (size_t)(m0 + wave * 32 + r) * Dc + n0;
        out[ro + col]      = c0[i] + bo0;
        out[ro + 32 + col] = c1[i] + bo1;
    }
}

// ---------------------------------------------------------------------------
extern "C" void kernel_launch(void* const* d_in, const int* in_sizes, int n_in,
                              void* d_out, int out_size, void* d_ws, size_t ws_size,
                              hipStream_t stream)
{
    const float* x    = (const float*)d_in[0];
    const float* mask = (const float*)d_in[1];
    const float* Wq   = (const float*)d_in[2];
    const float* bq   = (const float*)d_in[3];
    const float* Wk   = (const float*)d_in[4];
    const float* bk   = (const float*)d_in[5];
    const float* Wv   = (const float*)d_in[6];
    const float* bv   = (const float*)d_in[7];
    const float* Wo   = (const float*)d_in[8];
    const float* bo   = (const float*)d_in[9];
    float* out = (float*)d_out;

    constexpr size_t NQ = (size_t)Hc * Bc * Sc * Ec;  // 3,145,728
    f16* x16    = (f16*)d_ws;                      // 4096*768
    f16* Wt16   = x16 + (size_t)BSc * Dc;          // 2304*768
    f16* Wot16  = Wt16 + (size_t)3 * Dc * Dc;      // 768*768
    f16* q16    = Wot16 + (size_t)Dc * Dc;
    f16* kswz   = q16 + NQ;
    f16* vswz   = kswz + NQ;
    f16* obuf16 = vswz + NQ;                       // 4096*768
    float* bias_cat = (float*)(obuf16 + NQ);       // 2304 floats

    prep_kernel<<<2121, 256, 0, stream>>>(x, Wq, Wk, Wv, bq, bk, bv, Wo,
                                          x16, Wt16, Wot16, bias_cat);

    gemm_qkv_kernel<<<dim3(BSc / 128, 2304 / 128), 256, 0, stream>>>(
        x16, Wt16, bias_cat, q16, kswz, vswz);

    flash_attn_kernel<<<768, 128, 0, stream>>>(
        q16, kswz, vswz, mask, obuf16);

    gemm_out_kernel<<<dim3(BSc / 128, Dc / 64), 256, 0, stream>>>(
        obuf16, Wot16, bo, out);
}

// Round 4
// 618.675 us; speedup vs baseline: 1.0208x; 1.0208x over previous
//
#include <hip/hip_runtime.h>
#include <hip/hip_bf16.h>
#include <cmath>

// Problem constants
constexpr int Bc  = 2;
constexpr int Sc  = 2048;
constexpr int Dc  = 768;
constexpr int Hc  = 12;
constexpr int Ec  = 64;          // d_head
constexpr int BSc = Bc * Sc;     // 4096

typedef _Float16 f16;
typedef __attribute__((ext_vector_type(8)))  _Float16 half8;    // MFMA A/B frag (4 VGPR)
typedef __attribute__((ext_vector_type(16))) float    floatx16; // MFMA C/D (16 VGPR)

typedef __attribute__((address_space(3))) void       lds_void;
typedef __attribute__((address_space(1))) const void glb_cvoid;

// K swizzle: blob per (hb, kt(64), ks(4)), 512 halves: lane(hf*32+col)*8+j =
//   K[hb][key=kt*32+col][e=ks*16+hf*8+j]
// V swizzle: blob per (hb, kt(64), ks2(2), vh(2)), 512 halves: lane*8+j =
//   V[hb][key=kt*32+ks2*16+hf*8+j][e=vh*32+col]   (i.e. V^T fragment order)
//
// GEMM LDS tiles use a T2-style XOR swizzle (both-sides-or-neither, rule #21):
// global source column is pre-swizzled per lane (lseg ^ lrow) so the LINEAR
// global_load_lds write lands element (row, col ^ ((row&7)<<3)) at LDS slot
// (row, col); fragment reads apply the same XOR. Kills the 32-way bank
// conflict of the 128 B-pitch column read.
//
// GEMM K-loop: double-buffered (T3-minimum 2-phase), STAGE(t+1) issued before
// computing tile t, one barrier per step.
//
// Attention mask prefetch: DISTANCE 1 (ma/mb ping-pong). Distance-2 was
// measured −12 µs (R3): +32 VGPR pushed the kernel to the 256-cap edge
// (spill/scheduling loss) — reverted.

// ---------------------------------------------------------------------------
// Kernel 0: prep — x fp32->fp16; W transposes to B-operand [n][k] fp16; bias.
// ---------------------------------------------------------------------------
__global__ __launch_bounds__(256) void prep_kernel(
    const float* __restrict__ x,
    const float* __restrict__ Wq, const float* __restrict__ Wk, const float* __restrict__ Wv,
    const float* __restrict__ bq, const float* __restrict__ bk, const float* __restrict__ bv,
    const float* __restrict__ Wo,
    f16* __restrict__ x16, f16* __restrict__ Wt16, f16* __restrict__ Wot16,
    float* __restrict__ bias_cat)
{
    __shared__ __align__(16) float Ts[64][65];
    const int t = threadIdx.x;
    int bid = blockIdx.x;

    if (bid < 1536) {          // ---- x convert ----
        const size_t base = (size_t)bid * 2048 + t * 8;
        const float4 v0 = *(const float4*)(x + base);
        const float4 v1 = *(const float4*)(x + base + 4);
        half8 hv;
        hv[0] = (f16)v0.x; hv[1] = (f16)v0.y; hv[2] = (f16)v0.z; hv[3] = (f16)v0.w;
        hv[4] = (f16)v1.x; hv[5] = (f16)v1.y; hv[6] = (f16)v1.z; hv[7] = (f16)v1.w;
        *(half8*)(x16 + base) = hv;
        return;
    }
    bid -= 1536;
    if (bid < 432) {           // ---- qkv weight transpose ----
        const int proj = bid / 144, rem = bid % 144, h = rem / 12, dt = rem % 12;
        const float* W = ((proj == 0) ? Wq : (proj == 1) ? Wk : Wv) + (size_t)h * Dc * Ec;
        const int c = t & 63, rr = t >> 6;
        #pragma unroll
        for (int r0 = 0; r0 < 64; r0 += 4) {
            const int d = rr + r0;
            Ts[d][c] = W[(size_t)(dt * 64 + d) * Ec + c];
        }
        __syncthreads();
        #pragma unroll
        for (int r0 = 0; r0 < 64; r0 += 4) {
            const int e = rr + r0;
            Wt16[(size_t)(proj * 768 + h * 64 + e) * Dc + dt * 64 + c] = (f16)Ts[c][e];
        }
        return;
    }
    bid -= 432;
    if (bid < 144) {           // ---- Wo transpose ----
        const int rt = bid / 12, ct = bid % 12;
        const int c = t & 63, rr = t >> 6;
        #pragma unroll
        for (int r0 = 0; r0 < 64; r0 += 4) {
            const int d = rr + r0;
            Ts[d][c] = Wo[(size_t)(rt * 64 + d) * Dc + ct * 64 + c];
        }
        __syncthreads();
        #pragma unroll
        for (int r0 = 0; r0 < 64; r0 += 4) {
            const int e = rr + r0;
            Wot16[(size_t)(ct * 64 + e) * Dc + rt * 64 + c] = (f16)Ts[c][e];
        }
        return;
    }
    bid -= 144;
    {                          // ---- bias concat ----
        const int g = bid * 256 + t;
        if (g < 3 * 768) {
            const int proj = g / 768, idx = g % 768;
            const float* bb = (proj == 0) ? bq : (proj == 1) ? bk : bv;
            bias_cat[g] = bb[idx];
        }
    }
}

// ---------------------------------------------------------------------------
// Kernel 1: QKV GEMM (fp16 MFMA, double-buffered global_load_lds staging,
// XOR-swizzled LDS).
// ---------------------------------------------------------------------------
__global__ __launch_bounds__(256, 2) void gemm_qkv_kernel(
    const f16* __restrict__ x16, const f16* __restrict__ Wt16,
    const float* __restrict__ bias_cat,
    f16* __restrict__ q16, f16* __restrict__ kswz, f16* __restrict__ vswz)
{
    __shared__ __align__(16) unsigned char smem[65536];
    // buf b: As at b*32768, Bs at b*32768+16384 (each 128x64 f16 = 16384 B)
    f16 (*Cs)[136] = (f16(*)[136])smem;             // 128 x 136 = 34816 B (post-loop)

    const int t = threadIdx.x;
    const int wave = t >> 6, lane = t & 63;
    const int col = lane & 31, hf = lane >> 5;
    const int wr = wave & 1, wc = wave >> 1;
    const int m0 = blockIdx.x * 128, n0 = blockIdx.y * 128;
    const int lrow = lane >> 3, lseg = lane & 7;    // staging: 8 lanes per row
    const int sseg = lseg ^ lrow;                   // pre-swizzled source column
    const int sw   = (col & 7) << 3;                // read-side XOR (half index)

    floatx16 c00, c01, c10, c11;
    #pragma unroll
    for (int i = 0; i < 16; ++i) { c00[i] = 0.f; c01[i] = 0.f; c10[i] = 0.f; c11[i] = 0.f; }

#define QKV_STAGE(BUF, K0)                                                     \
    do {                                                                       \
        f16 (*As_)[64] = (f16(*)[64])(smem + (BUF) * 32768);                   \
        f16 (*Bs_)[64] = (f16(*)[64])(smem + (BUF) * 32768 + 16384);           \
        _Pragma("unroll")                                                      \
        for (int i_ = 0; i_ < 4; ++i_) {                                       \
            const int r_ = wave * 32 + i_ * 8;                                 \
            __builtin_amdgcn_global_load_lds(                                  \
                (glb_cvoid*)(x16 + (size_t)(m0 + r_ + lrow) * Dc + (K0) + sseg * 8), \
                (lds_void*)&As_[r_][0], 16, 0, 0);                             \
            __builtin_amdgcn_global_load_lds(                                  \
                (glb_cvoid*)(Wt16 + (size_t)(n0 + r_ + lrow) * Dc + (K0) + sseg * 8), \
                (lds_void*)&Bs_[r_][0], 16, 0, 0);                             \
        }                                                                      \
    } while (0)

    QKV_STAGE(0, 0);
    __syncthreads();
    for (int tt = 0; tt < 12; ++tt) {
        if (tt + 1 < 12) QKV_STAGE((tt + 1) & 1, (tt + 1) * 64);
        f16 (*As)[64] = (f16(*)[64])(smem + (tt & 1) * 32768);
        f16 (*Bs)[64] = (f16(*)[64])(smem + (tt & 1) * 32768 + 16384);
        #pragma unroll
        for (int ks = 0; ks < 4; ++ks) {
            const int fo = (ks * 16 + hf * 8) ^ sw;
            const half8 a0 = *(const half8*)&As[wr * 64 + col][fo];
            const half8 a1 = *(const half8*)&As[wr * 64 + 32 + col][fo];
            const half8 b0 = *(const half8*)&Bs[wc * 64 + col][fo];
            const half8 b1 = *(const half8*)&Bs[wc * 64 + 32 + col][fo];
            c00 = __builtin_amdgcn_mfma_f32_32x32x16_f16(a0, b0, c00, 0, 0, 0);
            c01 = __builtin_amdgcn_mfma_f32_32x32x16_f16(a0, b1, c01, 0, 0, 0);
            c10 = __builtin_amdgcn_mfma_f32_32x32x16_f16(a1, b0, c10, 0, 0, 0);
            c11 = __builtin_amdgcn_mfma_f32_32x32x16_f16(a1, b1, c11, 0, 0, 0);
        }
        __syncthreads();   // next-tile staging complete; all reads of old buf done
    }
#undef QKV_STAGE

    const float bias0 = bias_cat[n0 + wc * 64 + col];
    const float bias1 = bias_cat[n0 + wc * 64 + 32 + col];
    #pragma unroll
    for (int i = 0; i < 16; ++i) {
        const int r = (i & 3) + 8 * (i >> 2) + 4 * hf;
        Cs[wr * 64 + r][wc * 64 + col]           = (f16)(c00[i] + bias0);
        Cs[wr * 64 + r][wc * 64 + 32 + col]      = (f16)(c01[i] + bias1);
        Cs[wr * 64 + 32 + r][wc * 64 + col]      = (f16)(c10[i] + bias0);
        Cs[wr * 64 + 32 + r][wc * 64 + 32 + col] = (f16)(c11[i] + bias1);
    }
    __syncthreads();

    const int proj = n0 / 768;
    const int h0   = (n0 - proj * 768) >> 6;   // first of two heads in this tile
    const int b    = m0 >> 11;
    const int s_in = m0 & 2047;
    const int kt0  = s_in >> 5;                // first of 4 key-tiles in m-range

    if (proj == 0) {
        const int row = t >> 1, seg = t & 1;
        const int h = h0 + seg;
        f16* gp = q16 + ((size_t)(h * Bc + b) * Sc + s_in + row) * Ec;
        #pragma unroll
        for (int j = 0; j < 8; ++j)
            *(half8*)(gp + j * 8) = *(const half8*)&Cs[row][seg * 64 + j * 8];
    } else if (proj == 1) {
        #pragma unroll
        for (int ch = 0; ch < 8; ++ch) {
            const int id = ch * 256 + t;            // 0..2047
            const int lane_ = id & 63;
            const int ks  = (id >> 6) & 3;
            const int ktp = (id >> 8) & 3;
            const int seg = (id >> 10) & 1;
            const int colp = lane_ & 31, hfp = lane_ >> 5;
            const int hb = (h0 + seg) * Bc + b;
            const half8 val = *(const half8*)&Cs[ktp * 32 + colp][seg * 64 + ks * 16 + hfp * 8];
            *(half8*)(kswz + ((size_t)((hb * 64 + kt0 + ktp) * 4 + ks) << 9) + lane_ * 8) = val;
        }
    } else {
        #pragma unroll
        for (int ch = 0; ch < 8; ++ch) {
            const int id = ch * 256 + t;
            const int lane_ = id & 63;
            const int ks2 = (id >> 6) & 1;
            const int vh  = (id >> 7) & 1;
            const int ktp = (id >> 8) & 3;
            const int seg = (id >> 10) & 1;
            const int colp = lane_ & 31, hfp = lane_ >> 5;
            const int hb = (h0 + seg) * Bc + b;
            const int e  = vh * 32 + colp;
            half8 val;
            #pragma unroll
            for (int j = 0; j < 8; ++j)
                val[j] = Cs[ktp * 32 + ks2 * 16 + hfp * 8 + j][seg * 64 + e];
            *(half8*)(vswz + ((size_t)(((hb * 64 + kt0 + ktp) * 2 + ks2) * 2 + vh) << 9) + lane_ * 8) = val;
        }
    }
}

// ---------------------------------------------------------------------------
// Kernel 2: fp16 MFMA flash attention. 128 threads = 2 waves; each wave owns
// 32 query rows and sweeps ALL 2048 keys (no key-half split, no combine).
// Mask loads go direct to VGPRs (nontemporal), double-buffered one key-tile
// ahead (distance-1; distance-2 measured −12 µs, VGPR-cap edge). Main loop
// is barrier-free. Two-pass softmax.
// ---------------------------------------------------------------------------
__global__ __launch_bounds__(128, 2) void flash_attn_kernel(
    const f16* __restrict__ q16, const f16* __restrict__ kswz,
    const f16* __restrict__ vswz, const float* __restrict__ mask,
    f16* __restrict__ obuf16)
{
    __shared__ _Float16 Plds[2][32][44];             // 5.5 KB per-wave P tiles

    // XCD-aware decode: xcd = fblk&7 ; 3 hb per XCD -> K/V L2-resident
    const int fblk = blockIdx.x;            // 0..767
    const int kk   = fblk >> 3;             // 0..95
    const int hb   = (fblk & 7) + 8 * (kk >> 5);   // 0..23
    const int rb   = kk & 31;
    const int h    = hb >> 1;
    const int b    = hb & 1;

    const int t    = threadIdx.x;
    const int wave = t >> 6;     // row group (0/1)
    const int lane = t & 63;
    const int col  = lane & 31;
    const int hf   = lane >> 5;
    const int row0 = rb * 64 + wave * 32;

    const f16* qb  = q16  + ((size_t)hb * Sc + row0) * Ec;
    const f16* kbz = kswz + ((size_t)hb << 17);
    const f16* vbz = vswz + ((size_t)hb << 17);
    const float* mband = mask + ((size_t)hb * Sc + rb * 64) * Sc;  // block's 64-row band

    half8 qfrag[4];
    #pragma unroll
    for (int ks = 0; ks < 4; ++ks)
        qfrag[ks] = *(const half8*)(qb + (size_t)col * Ec + ks * 16 + hf * 8);

    constexpr int NT = Sc / 32;   // 64 key tiles

    // ======== PASS 1: row max (mask <= 0 ⇒ exp(s-mrow) <= 1 stays safe) ====
    float vmax[16];
    #pragma unroll
    for (int i = 0; i < 16; ++i) vmax[i] = -3e38f;

    half8 kreg[4];
    {
        const f16* kp = kbz + lane * 8;
        #pragma unroll
        for (int ks = 0; ks < 4; ++ks) kreg[ks] = *(const half8*)(kp + (ks << 9));
    }
    #pragma unroll 2
    for (int kt = 0; kt < NT; ++kt) {
        floatx16 c;
        #pragma unroll
        for (int i = 0; i < 16; ++i) c[i] = 0.f;
        #pragma unroll
        for (int ks = 0; ks < 4; ++ks)
            c = __builtin_amdgcn_mfma_f32_32x32x16_f16(qfrag[ks], kreg[ks], c, 0, 0, 0);
        if (kt + 1 < NT) {
            const f16* kp = kbz + ((size_t)(kt + 1) << 11) + lane * 8;
            #pragma unroll
            for (int ks = 0; ks < 4; ++ks) kreg[ks] = *(const half8*)(kp + (ks << 9));
        }
        #pragma unroll
        for (int i = 0; i < 16; ++i) vmax[i] = fmaxf(vmax[i], c[i]);
    }
    float mrow[16];
    #pragma unroll
    for (int i = 0; i < 16; ++i) {
        float v = vmax[i];
        v = fmaxf(v, __shfl_xor(v, 1));
        v = fmaxf(v, __shfl_xor(v, 2));
        v = fmaxf(v, __shfl_xor(v, 4));
        v = fmaxf(v, __shfl_xor(v, 8));
        v = fmaxf(v, __shfl_xor(v, 16));
        mrow[i] = v;
    }

    // ======== PASS 2: exp + PV; mask in registers, 1 tile ahead, NT loads ==
    floatx16 o0, o1;
    float lsum[16];
    #pragma unroll
    for (int i = 0; i < 16; ++i) { o0[i] = 0.f; o1[i] = 0.f; lsum[i] = 0.f; }

    // lane's mask base: rows (wave*32 + 4*hf + roff), column `col` of the band
    const float* mlane = mband + (size_t)(wave * 32 + 4 * hf) * Sc + col;

    float ma[16], mb[16];
    #pragma unroll
    for (int i = 0; i < 16; ++i)
        ma[i] = __builtin_nontemporal_load(
            mlane + (size_t)((i & 3) + 8 * (i >> 2)) * Sc);

    {   // K tile 0 prefetch (L2-fast, issued after the HBM mask loads)
        const f16* kp = kbz + lane * 8;
        #pragma unroll
        for (int ks = 0; ks < 4; ++ks) kreg[ks] = *(const half8*)(kp + (ks << 9));
    }

    // Tile body. Issue order matters for counted waitcnts:
    //   V(kt) -> mask(kt+1) -> QK mfma -> K(kt+1) -> exp(uses MC) -> PV.
#define ATT_TILE(KT, MC, MN)                                                   \
    do {                                                                       \
        const int kt_ = (KT);                                                  \
        const f16* vp_ = vbz + ((size_t)kt_ << 11) + lane * 8;                 \
        const half8 va_ = *(const half8*)(vp_);                                \
        const half8 vb_ = *(const half8*)(vp_ + (1 << 9));                     \
        const half8 vc_ = *(const half8*)(vp_ + (2 << 9));                     \
        const half8 vd_ = *(const half8*)(vp_ + (3 << 9));                     \
        if (kt_ + 1 < NT) {                                                    \
            const float* mp_ = mlane + (kt_ + 1) * 32;                         \
            _Pragma("unroll")                                                  \
            for (int i = 0; i < 16; ++i)                                       \
                MN[i] = __builtin_nontemporal_load(                            \
                    mp_ + (size_t)((i & 3) + 8 * (i >> 2)) * Sc);              \
        }                                                                      \
        floatx16 c_;                                                           \
        _Pragma("unroll")                                                      \
        for (int i = 0; i < 16; ++i) c_[i] = 0.f;                              \
        _Pragma("unroll")                                                      \
        for (int ks = 0; ks < 4; ++ks)                                         \
            c_ = __builtin_amdgcn_mfma_f32_32x32x16_f16(qfrag[ks], kreg[ks],   \
                                                        c_, 0, 0, 0);          \
        if (kt_ + 1 < NT) {                                                    \
            const f16* kp_ = kbz + ((size_t)(kt_ + 1) << 11) + lane * 8;       \
            _Pragma("unroll")                                                  \
            for (int ks = 0; ks < 4; ++ks)                                     \
                kreg[ks] = *(const half8*)(kp_ + (ks << 9));                   \
        }                                                                      \
        _Pragma("unroll")                                                      \
        for (int i = 0; i < 16; ++i) {                                         \
            const int r_ = (i & 3) + 8 * (i >> 2) + 4 * hf;                    \
            const float p_ = __expf(c_[i] + MC[i] - mrow[i]);  /* <=1 */       \
            lsum[i] += p_;                                                     \
            Plds[wave][r_][col] = (f16)p_;                                     \
        }                                                                      \
        /* same-wave RAW through LDS (per-wave private slice) */               \
        asm volatile("s_waitcnt lgkmcnt(0)" ::: "memory");                     \
        _Pragma("unroll")                                                      \
        for (int ks2 = 0; ks2 < 2; ++ks2) {                                    \
            const half8 pf_ = *(const half8*)(&Plds[wave][col][ks2 * 16 + hf * 8]); \
            o0 = __builtin_amdgcn_mfma_f32_32x32x16_f16(                       \
                pf_, (ks2 == 0) ? va_ : vc_, o0, 0, 0, 0);                     \
            o1 = __builtin_amdgcn_mfma_f32_32x32x16_f16(                       \
                pf_, (ks2 == 0) ? vb_ : vd_, o1, 0, 0, 0);                     \
        }                                                                      \
    } while (0)

    for (int kt2 = 0; kt2 < NT; kt2 += 2) {
        ATT_TILE(kt2,     ma, mb);
        ATT_TILE(kt2 + 1, mb, ma);
    }
#undef ATT_TILE

    // final l reduction + normalize + store (no cross-wave combine needed)
    #pragma unroll
    for (int i = 0; i < 16; ++i) {
        float v = lsum[i];
        v += __shfl_xor(v, 1);
        v += __shfl_xor(v, 2);
        v += __shfl_xor(v, 4);
        v += __shfl_xor(v, 8);
        v += __shfl_xor(v, 16);
        const float inv = 1.f / v;
        const int r = (i & 3) + 8 * (i >> 2) + 4 * hf;
        const size_t orow = ((size_t)b * Sc + row0 + r) * Dc + h * Ec;
        obuf16[orow + col]      = (f16)(o0[i] * inv);
        obuf16[orow + 32 + col] = (f16)(o1[i] * inv);
    }
}

// ---------------------------------------------------------------------------
// Kernel 3: output GEMM (fp16 MFMA, double-buffered global_load_lds staging,
// XOR-swizzled LDS).
// ---------------------------------------------------------------------------
__global__ __launch_bounds__(256, 2) void gemm_out_kernel(
    const f16* __restrict__ a16, const f16* __restrict__ Wot16,
    const float* __restrict__ bo, float* __restrict__ out)
{
    __shared__ __align__(16) unsigned char smem[49152];
    // buf b: As at b*24576 (128x64 = 16384 B), Bs at b*24576+16384 (64x64 = 8192 B)

    const int t = threadIdx.x;
    const int wave = t >> 6, lane = t & 63;
    const int col = lane & 31, hf = lane >> 5;
    const int m0 = blockIdx.x * 128, n0 = blockIdx.y * 64;
    const int lrow = lane >> 3, lseg = lane & 7;
    const int sseg = lseg ^ lrow;                   // pre-swizzled source column
    const int sw   = (col & 7) << 3;                // read-side XOR (half index)

    floatx16 c0, c1;
    #pragma unroll
    for (int i = 0; i < 16; ++i) { c0[i] = 0.f; c1[i] = 0.f; }

#define OUT_STAGE(BUF, K0)                                                     \
    do {                                                                       \
        f16 (*As_)[64] = (f16(*)[64])(smem + (BUF) * 24576);                   \
        f16 (*Bs_)[64] = (f16(*)[64])(smem + (BUF) * 24576 + 16384);           \
        _Pragma("unroll")                                                      \
        for (int i_ = 0; i_ < 4; ++i_) {                                       \
            const int r_ = wave * 32 + i_ * 8;                                 \
            __builtin_amdgcn_global_load_lds(                                  \
                (glb_cvoid*)(a16 + (size_t)(m0 + r_ + lrow) * Dc + (K0) + sseg * 8), \
                (lds_void*)&As_[r_][0], 16, 0, 0);                             \
        }                                                                      \
        {                                                                      \
            const int r_ = wave * 16;                                          \
            __builtin_amdgcn_global_load_lds(                                  \
                (glb_cvoid*)(Wot16 + (size_t)(n0 + r_ + lrow) * Dc + (K0) + sseg * 8), \
                (lds_void*)&Bs_[r_][0], 16, 0, 0);                             \
            __builtin_amdgcn_global_load_lds(                                  \
                (glb_cvoid*)(Wot16 + (size_t)(n0 + r_ + 8 + lrow) * Dc + (K0) + sseg * 8), \
                (lds_void*)&Bs_[r_ + 8][0], 16, 0, 0);                         \
        }                                                                      \
    } while (0)

    OUT_STAGE(0, 0);
    __syncthreads();
    for (int tt = 0; tt < 12; ++tt) {
        if (tt + 1 < 12) OUT_STAGE((tt + 1) & 1, (tt + 1) * 64);
        f16 (*As)[64] = (f16(*)[64])(smem + (tt & 1) * 24576);
        f16 (*Bs)[64] = (f16(*)[64])(smem + (tt & 1) * 24576 + 16384);
        #pragma unroll
        for (int ks = 0; ks < 4; ++ks) {
            const int fo = (ks * 16 + hf * 8) ^ sw;
            const half8 a  = *(const half8*)&As[wave * 32 + col][fo];
            const half8 b0 = *(const half8*)&Bs[col][fo];
            const half8 b1 = *(const half8*)&Bs[32 + col][fo];
            c0 = __builtin_amdgcn_mfma_f32_32x32x16_f16(a, b0, c0, 0, 0, 0);
            c1 = __builtin_amdgcn_mfma_f32_32x32x16_f16(a, b1, c1, 0, 0, 0);
        }
        __syncthreads();
    }
#undef OUT_STAGE

    const float bo0 = bo[n0 + col], bo1 = bo[n0 + 32 + col];
    #pragma unroll
    for (int i = 0; i < 16; ++i) {
        const int r = (i & 3) + 8 * (i >> 2) + 4 * hf;
        const size_t ro = (size_t)(m0 + wave * 32 + r) * Dc + n0;
        out[ro + col]      = c0[i] + bo0;
        out[ro + 32 + col] = c1[i] + bo1;
    }
}

// ---------------------------------------------------------------------------
extern "C" void kernel_launch(void* const* d_in, const int* in_sizes, int n_in,
                              void* d_out, int out_size, void* d_ws, size_t ws_size,
                              hipStream_t stream)
{
    const float* x    = (const float*)d_in[0];
    const float* mask = (const float*)d_in[1];
    const float* Wq   = (const float*)d_in[2];
    const float* bq   = (const float*)d_in[3];
    const float* Wk   = (const float*)d_in[4];
    const float* bk   = (const float*)d_in[5];
    const float* Wv   = (const float*)d_in[6];
    const float* bv   = (const float*)d_in[7];
    const float* Wo   = (const float*)d_in[8];
    const float* bo   = (const float*)d_in[9];
    float* out = (float*)d_out;

    constexpr size_t NQ = (size_t)Hc * Bc * Sc * Ec;  // 3,145,728
    f16* x16    = (f16*)d_ws;                      // 4096*768
    f16* Wt16   = x16 + (size_t)BSc * Dc;          // 2304*768
    f16* Wot16  = Wt16 + (size_t)3 * Dc * Dc;      // 768*768
    f16* q16    = Wot16 + (size_t)Dc * Dc;
    f16* kswz   = q16 + NQ;
    f16* vswz   = kswz + NQ;
    f16* obuf16 = vswz + NQ;                       // 4096*768
    float* bias_cat = (float*)(obuf16 + NQ);       // 2304 floats

    prep_kernel<<<2121, 256, 0, stream>>>(x, Wq, Wk, Wv, bq, bk, bv, Wo,
                                          x16, Wt16, Wot16, bias_cat);

    gemm_qkv_kernel<<<dim3(BSc / 128, 2304 / 128), 256, 0, stream>>>(
        x16, Wt16, bias_cat, q16, kswz, vswz);

    flash_attn_kernel<<<768, 128, 0, stream>>>(
        q16, kswz, vswz, mask, obuf16);

    gemm_out_kernel<<<dim3(BSc / 128, Dc / 64), 256, 0, stream>>>(
        obuf16, Wot16, bo, out);
}